// Round 1
// baseline (749.823 us; speedup 1.0000x reference)
//
#include <hip/hip_runtime.h>

// Problem constants (fixed by the reference)
#define N_NODES 100000
#define N_EDGES 1600000
#define HF      128
#define CAP     64          // per-node in-edge bucket capacity (Poisson(16) tail ~1e-20)
#define RESC    0.5f
#define LN_EPS  1e-5f

#define GEMM_THREADS 512
#define MT  32              // rows per GEMM block
#define RPT 2               // rows per thread (MT*128 outputs / 512 threads / 4 cols)

// ---------------------------------------------------------------------------
// Build per-dst bucket lists + out-degree counts. int atomics only.
// ---------------------------------------------------------------------------
__global__ __launch_bounds__(256) void build_kernel(
    const int* __restrict__ src, const int* __restrict__ dst,
    int* __restrict__ deg_out, int* __restrict__ cnt, int* __restrict__ bucket)
{
    int e = blockIdx.x * 256 + threadIdx.x;
    if (e >= N_EDGES) return;
    int s = src[e], d = dst[e];
    atomicAdd(deg_out + s, 1);
    int slot = atomicAdd(cnt + d, 1);
    if (slot < CAP) bucket[(size_t)d * CAP + slot] = s;
}

__global__ __launch_bounds__(256) void norm_kernel(
    const int* __restrict__ deg_out, const int* __restrict__ cnt,
    float* __restrict__ ns, float* __restrict__ nd)
{
    int i = blockIdx.x * 256 + threadIdx.x;
    if (i >= N_NODES) return;
    ns[i] = rsqrtf((float)max(deg_out[i], 1));
    nd[i] = rsqrtf((float)max(cnt[i], 1));
}

// ---------------------------------------------------------------------------
// Aggregation: one 64-lane wave per node. agg[v] = nd[v] * sum_e ns[s]*hin[s].
// Each lane owns 2 features (float2) -> 512B coalesced row reads.
// ---------------------------------------------------------------------------
__global__ __launch_bounds__(256) void agg_kernel(
    const float* __restrict__ hin, const int* __restrict__ bucket,
    const int* __restrict__ cnt, const float* __restrict__ ns,
    const float* __restrict__ nd, float* __restrict__ agg)
{
    int node = blockIdx.x * 4 + (threadIdx.x >> 6);
    if (node >= N_NODES) return;
    int lane = threadIdx.x & 63;
    int deg = cnt[node];
    if (deg > CAP) deg = CAP;
    const int* bk = bucket + (size_t)node * CAP;

    float ax = 0.f, ay = 0.f;
    int k = 0;
    for (; k + 1 < deg; k += 2) {
        int s0 = bk[k], s1 = bk[k + 1];
        float c0 = ns[s0], c1 = ns[s1];
        float2 v0 = *(const float2*)(hin + (size_t)s0 * HF + lane * 2);
        float2 v1 = *(const float2*)(hin + (size_t)s1 * HF + lane * 2);
        ax = fmaf(c0, v0.x, ax); ay = fmaf(c0, v0.y, ay);
        ax = fmaf(c1, v1.x, ax); ay = fmaf(c1, v1.y, ay);
    }
    if (k < deg) {
        int s = bk[k];
        float c = ns[s];
        float2 v = *(const float2*)(hin + (size_t)s * HF + lane * 2);
        ax = fmaf(c, v.x, ax); ay = fmaf(c, v.y, ay);
    }
    float m = nd[node];
    *(float2*)(agg + (size_t)node * HF + lane * 2) = make_float2(ax * m, ay * m);
}

// ---------------------------------------------------------------------------
// Fused GEMM: t = A @ W + bias [+ RES*ori], then
//   MODE 0: store t -> out2 (=ori buffer, lives in d_out); LN/ReLU -> hout
//   MODE 1: LN/ReLU -> hout only
//   MODE 2: store t -> out2 (final output)
// W staged in 64KiB LDS. A rows read via broadcast float4 (L1 hits).
// One block owns full 128-wide rows -> LN reduction = 32-lane shuffle.
// ---------------------------------------------------------------------------
template <int MODE>
__global__ __launch_bounds__(GEMM_THREADS) void gemm_fused(
    const float* __restrict__ A, const float* __restrict__ Wp,
    const float* __restrict__ bias, const float* __restrict__ lng,
    const float* __restrict__ lnb, const float* __restrict__ ori,
    float* __restrict__ hout, float* __restrict__ out2)
{
    __shared__ float sW[HF * HF];   // 64 KiB
    const int tid = threadIdx.x;
    const int row0 = blockIdx.x * MT;

    const float4* W4 = (const float4*)Wp;
    float4* sW4 = (float4*)sW;
#pragma unroll
    for (int i = 0; i < (HF * HF / 4) / GEMM_THREADS; ++i)
        sW4[tid + i * GEMM_THREADS] = W4[tid + i * GEMM_THREADS];
    __syncthreads();

    const int cg = tid & 31;        // col group: cols cg*4 .. cg*4+3
    const int rg = tid >> 5;        // row group: rows rg*RPT .. +RPT-1

    const float* Ar0 = A + (size_t)(row0 + rg * RPT) * HF;
    const float* Ar1 = Ar0 + HF;

    float acc[RPT][4] = {};
    for (int k = 0; k < HF; k += 4) {
        float4 a0 = *(const float4*)(Ar0 + k);
        float4 a1 = *(const float4*)(Ar1 + k);
#pragma unroll
        for (int j = 0; j < 4; ++j) {
            float4 w = *(const float4*)(sW + (k + j) * HF + cg * 4);
            float av0 = j == 0 ? a0.x : j == 1 ? a0.y : j == 2 ? a0.z : a0.w;
            float av1 = j == 0 ? a1.x : j == 1 ? a1.y : j == 2 ? a1.z : a1.w;
            acc[0][0] = fmaf(av0, w.x, acc[0][0]);
            acc[0][1] = fmaf(av0, w.y, acc[0][1]);
            acc[0][2] = fmaf(av0, w.z, acc[0][2]);
            acc[0][3] = fmaf(av0, w.w, acc[0][3]);
            acc[1][0] = fmaf(av1, w.x, acc[1][0]);
            acc[1][1] = fmaf(av1, w.y, acc[1][1]);
            acc[1][2] = fmaf(av1, w.z, acc[1][2]);
            acc[1][3] = fmaf(av1, w.w, acc[1][3]);
        }
    }

    const float4 bia = *(const float4*)(bias + cg * 4);
    float4 gg, bb;
    if constexpr (MODE != 2) {
        gg = *(const float4*)(lng + cg * 4);
        bb = *(const float4*)(lnb + cg * 4);
    }

#pragma unroll
    for (int r = 0; r < RPT; ++r) {
        const int row = row0 + rg * RPT + r;
        const size_t off = (size_t)row * HF + cg * 4;
        float t0 = acc[r][0] + bia.x, t1 = acc[r][1] + bia.y;
        float t2 = acc[r][2] + bia.z, t3 = acc[r][3] + bia.w;
        if constexpr (MODE != 0) {
            float4 o = *(const float4*)(ori + off);
            t0 = fmaf(RESC, o.x, t0); t1 = fmaf(RESC, o.y, t1);
            t2 = fmaf(RESC, o.z, t2); t3 = fmaf(RESC, o.w, t3);
        }
        if constexpr (MODE == 0)
            *(float4*)(out2 + off) = make_float4(t0, t1, t2, t3);
        if constexpr (MODE == 2) {
            *(float4*)(out2 + off) = make_float4(t0, t1, t2, t3);
        } else {
            // LayerNorm over the 128 cols of this row (32 lanes hold it)
            float s  = t0 + t1 + t2 + t3;
            float ss = t0 * t0 + t1 * t1 + t2 * t2 + t3 * t3;
#pragma unroll
            for (int m = 16; m >= 1; m >>= 1) {
                s  += __shfl_xor(s, m);
                ss += __shfl_xor(ss, m);
            }
            float mu   = s * (1.0f / HF);
            float var  = ss * (1.0f / HF) - mu * mu;
            float rinv = rsqrtf(var + LN_EPS);
            float y0 = fmaxf(0.f, (t0 - mu) * rinv * gg.x + bb.x);
            float y1 = fmaxf(0.f, (t1 - mu) * rinv * gg.y + bb.y);
            float y2 = fmaxf(0.f, (t2 - mu) * rinv * gg.z + bb.z);
            float y3 = fmaxf(0.f, (t3 - mu) * rinv * gg.w + bb.w);
            *(float4*)(hout + off) = make_float4(y0, y1, y2, y3);
        }
    }
}

// ---------------------------------------------------------------------------
extern "C" void kernel_launch(void* const* d_in, const int* in_sizes, int n_in,
                              void* d_out, int out_size, void* d_ws, size_t ws_size,
                              hipStream_t stream)
{
    const float* x   = (const float*)d_in[0];
    const float* W0  = (const float*)d_in[1];
    const float* Ws  = (const float*)d_in[2];
    const float* b   = (const float*)d_in[3];
    const float* lng = (const float*)d_in[4];
    const float* lnb = (const float*)d_in[5];
    const int*   src = (const int*)d_in[6];
    const int*   dst = (const int*)d_in[7];
    float* out = (float*)d_out;

    // workspace layout (512B-aligned chunks), total ~129.6 MB
    char* ws = (char*)d_ws;
    int*   cnt     = (int*)(ws + 0);            // N ints
    int*   deg_out = (int*)(ws + 400384);       // N ints
    float* ns      = (float*)(ws + 800768);     // N f32
    float* nd      = (float*)(ws + 1201152);    // N f32
    int*   bucket  = (int*)(ws + 1601536);      // N*CAP ints = 25.6 MB
    float* hin     = (float*)(ws + 27201536);   // N*128 f32 = 51.2 MB
    float* agg     = (float*)(ws + 78401536);   // N*128 f32 = 51.2 MB

    // zero cnt + deg_out (contiguous region)
    hipMemsetAsync(cnt, 0, 800768, stream);

    build_kernel<<<(N_EDGES + 255) / 256, 256, 0, stream>>>(src, dst, deg_out, cnt, bucket);
    norm_kernel<<<(N_NODES + 255) / 256, 256, 0, stream>>>(deg_out, cnt, ns, nd);

    // layer 0: agg0 = norm-agg(x); ori(d_out) = agg0@W0+b0; hin = relu(LN1(ori))
    agg_kernel<<<N_NODES / 4, 256, 0, stream>>>(x, bucket, cnt, ns, nd, agg);
    gemm_fused<0><<<N_NODES / MT, GEMM_THREADS, 0, stream>>>(
        agg, W0, b, lng + HF, lnb + HF, nullptr, hin, out);

    // layer 1: agg1 = norm-agg(hin); h1 = agg1@Ws0+b1+0.5*ori; hin = relu(LN2(h1))
    agg_kernel<<<N_NODES / 4, 256, 0, stream>>>(hin, bucket, cnt, ns, nd, agg);
    gemm_fused<1><<<N_NODES / MT, GEMM_THREADS, 0, stream>>>(
        agg, Ws, b + HF, lng + 2 * HF, lnb + 2 * HF, out, hin, nullptr);

    // layer 2: agg2 = norm-agg(hin); out = agg2@Ws1+b2+0.5*ori
    agg_kernel<<<N_NODES / 4, 256, 0, stream>>>(hin, bucket, cnt, ns, nd, agg);
    gemm_fused<2><<<N_NODES / MT, GEMM_THREADS, 0, stream>>>(
        agg, Ws + HF * HF, b + 2 * HF, nullptr, nullptr, out, nullptr, out);
}